// Round 1
// baseline (58.092 us; speedup 1.0000x reference)
//
#include <hip/hip_runtime.h>
#include <math.h>

#define B_ 128
#define S_ 512
#define E_ 64

typedef short bf16x8 __attribute__((ext_vector_type(8)));
typedef float f32x4 __attribute__((ext_vector_type(4)));

__device__ __forceinline__ unsigned short f2bf(float f) {
  union { float f; unsigned int u; } v; v.f = f;
  unsigned int u = v.u;
  unsigned int r = (u + 0x7fffu + ((u >> 16) & 1u)) >> 16;
  return (unsigned short)r;
}

// One wave (64 lanes) per row of 64 elements: L2-normalize; for item rows also
// fold in w * cluster_weight. Emit bf16.
__global__ void prep_kernel(const float* __restrict__ ue,
                            const float* __restrict__ ve,
                            const float* __restrict__ cw,
                            const float* __restrict__ pw,
                            unsigned short* __restrict__ ubf,
                            unsigned short* __restrict__ vbf) {
  int gid = blockIdx.x * blockDim.x + threadIdx.x;
  int wid = gid >> 6;   // one wave per row
  int lane = gid & 63;  // one lane per element (E_ == 64)
  const int R = B_ * S_;
  bool isV = wid >= R;
  int row = isV ? (wid - R) : wid;
  const float* src = isV ? ve : ue;
  float x = src[(size_t)row * E_ + lane];
  float ss = x * x;
#pragma unroll
  for (int off = 32; off >= 1; off >>= 1) ss += __shfl_xor(ss, off);
  float scale = 1.0f / fmaxf(sqrtf(ss), 1e-7f);
  if (isV) scale *= pw[0] * cw[row];
  (isV ? vbf : ubf)[(size_t)row * E_ + lane] = f2bf(x * scale);
}

// Block = 256 threads = 4 waves. Each wave owns 16 s-rows of one batch b and
// scans all n in tiles of 16 via mfma_f32_16x16x32_bf16 (K = E = 64 -> 2 MFMAs).
// Running per-lane max (mask -> -inf), then shfl_xor max over the 16 col-lanes,
// sigmoid once per row.
__global__ void wmax_kernel(const unsigned short* __restrict__ ubf,
                            const unsigned short* __restrict__ vbf,
                            const float* __restrict__ mask,
                            const float* __restrict__ pb,
                            float* __restrict__ out) {
  int b = blockIdx.y;
  int lane = threadIdx.x & 63;
  int wave = threadIdx.x >> 6;
  int s0 = blockIdx.x * 64 + wave * 16;
  int col = lane & 15;  // A-row / B-col / C-col index
  int kg = lane >> 4;   // k-group
  const unsigned short* Ub = ubf + (size_t)b * S_ * E_;
  const unsigned short* Vb = vbf + (size_t)b * S_ * E_;

  // A fragments (fixed for the wave): A[row = s0+col][k = kg*8 + 0..7], +32
  bf16x8 a0 = *(const bf16x8*)(Ub + (size_t)(s0 + col) * E_ + kg * 8);
  bf16x8 a1 = *(const bf16x8*)(Ub + (size_t)(s0 + col) * E_ + kg * 8 + 32);

  float rmax0 = -INFINITY, rmax1 = -INFINITY, rmax2 = -INFINITY, rmax3 = -INFINITY;
  const float* mb = mask + (size_t)b * S_;

  for (int n0 = 0; n0 < S_; n0 += 16) {
    bf16x8 b0 = *(const bf16x8*)(Vb + (size_t)(n0 + col) * E_ + kg * 8);
    bf16x8 b1 = *(const bf16x8*)(Vb + (size_t)(n0 + col) * E_ + kg * 8 + 32);
    f32x4 acc = {0.f, 0.f, 0.f, 0.f};
    acc = __builtin_amdgcn_mfma_f32_16x16x32_bf16(a0, b0, acc, 0, 0, 0);
    acc = __builtin_amdgcn_mfma_f32_16x16x32_bf16(a1, b1, acc, 0, 0, 0);
    bool keep = mb[n0 + col] > 0.5f;  // this lane's column n = n0 + col
    float v0 = keep ? acc[0] : -INFINITY;
    float v1 = keep ? acc[1] : -INFINITY;
    float v2 = keep ? acc[2] : -INFINITY;
    float v3 = keep ? acc[3] : -INFINITY;
    rmax0 = fmaxf(rmax0, v0);
    rmax1 = fmaxf(rmax1, v1);
    rmax2 = fmaxf(rmax2, v2);
    rmax3 = fmaxf(rmax3, v3);
  }

  // Max across the 16 column-lanes (xor 1,2,4,8 stays within the kg group).
  float r[4] = {rmax0, rmax1, rmax2, rmax3};
#pragma unroll
  for (int i = 0; i < 4; ++i) {
    float v = r[i];
    v = fmaxf(v, __shfl_xor(v, 1));
    v = fmaxf(v, __shfl_xor(v, 2));
    v = fmaxf(v, __shfl_xor(v, 4));
    v = fmaxf(v, __shfl_xor(v, 8));
    r[i] = v;
  }

  if (col == 0) {
    float bias = pb[0];
#pragma unroll
    for (int i = 0; i < 4; ++i) {
      int srow = s0 + kg * 4 + i;  // C row = (lane>>4)*4 + reg
      float v = r[i];
      float o = (v < -1e30f) ? 0.0f : 1.0f / (1.0f + expf(-(v + bias)));
      out[(size_t)b * S_ + srow] = o;
    }
  }
}

extern "C" void kernel_launch(void* const* d_in, const int* in_sizes, int n_in,
                              void* d_out, int out_size, void* d_ws, size_t ws_size,
                              hipStream_t stream) {
  const float* ue = (const float*)d_in[0];
  const float* ve = (const float*)d_in[1];
  const float* cw = (const float*)d_in[2];
  const float* mask = (const float*)d_in[3];
  const float* pw = (const float*)d_in[4];
  const float* pb = (const float*)d_in[5];
  float* out = (float*)d_out;

  unsigned short* ubf = (unsigned short*)d_ws;
  unsigned short* vbf = ubf + (size_t)B_ * S_ * E_;

  // prep: one wave per row, 2*B*S rows, 4 waves per 256-thread block
  int totalRows = 2 * B_ * S_;
  hipLaunchKernelGGL(prep_kernel, dim3(totalRows / 4), dim3(256), 0, stream,
                     ue, ve, cw, pw, ubf, vbf);

  // main: grid (S/64, B), 4 waves per block, 16 s-rows per wave
  hipLaunchKernelGGL(wmax_kernel, dim3(S_ / 64, B_), dim3(256), 0, stream,
                     ubf, vbf, mask, pb, out);
}

// Round 2
// 21.122 us; speedup vs baseline: 2.7504x; 2.7504x over previous
//
#include <hip/hip_runtime.h>
#include <math.h>

#define B_ 128
#define S_ 512
#define E_ 64
#define PAD_ 72  // bf16 elems per LDS row (144B): makes ds_read_b128 bank-uniform

typedef short bf16x8 __attribute__((ext_vector_type(8)));
typedef float f32x4 __attribute__((ext_vector_type(4)));

__device__ __forceinline__ unsigned short f2bf(float f) {
  union { float f; unsigned int u; } v; v.f = f;
  unsigned int u = v.u;
  return (unsigned short)((u + 0x7fffu + ((u >> 16) & 1u)) >> 16);
}

// One fused kernel. Block = 512 threads (8 waves) handles batch b = blk>>1,
// s-rows [ (blk&1)*256, +256 ). Phase 1: L2-normalize U (256 rows) and V (512
// rows, folding w*cw) into LDS bf16. Phase 2: MFMA max-scan from LDS, sigmoid.
__global__ __launch_bounds__(512) void fused_kernel(
    const float* __restrict__ ue, const float* __restrict__ ve,
    const float* __restrict__ cw, const float* __restrict__ mask,
    const float* __restrict__ pw, const float* __restrict__ pb,
    float* __restrict__ out) {
  __shared__ unsigned short vlds[S_ * PAD_];   // 73728 B
  __shared__ unsigned short ulds[256 * PAD_];  // 36864 B

  const int b = blockIdx.x >> 1;
  const int shalf = blockIdx.x & 1;
  const int tid = threadIdx.x;
  const int wv = tid >> 6;
  const int lane = tid & 63;
  const int c = lane & 15;  // 16-lane sub-group index (col / elem group)
  const int g = lane >> 4;  // row-within-4 / k-group

  const float w0 = pw[0];
  const float* __restrict__ vb = ve + (size_t)b * S_ * E_;
  const float* __restrict__ cwb = cw + (size_t)b * S_;
  const float* __restrict__ ub = ue + ((size_t)b * S_ + shalf * 256) * E_;

  // ---- Phase 1a: normalize V rows (wave wv owns rows [wv*64, +64)) ----
#pragma unroll 4
  for (int i = 0; i < 16; ++i) {
    int row = wv * 64 + i * 4 + g;
    f32x4 x = *(const f32x4*)(vb + (size_t)row * E_ + c * 4);
    float ss = x[0] * x[0] + x[1] * x[1] + x[2] * x[2] + x[3] * x[3];
    ss += __shfl_xor(ss, 1); ss += __shfl_xor(ss, 2);
    ss += __shfl_xor(ss, 4); ss += __shfl_xor(ss, 8);
    float scale = (1.0f / fmaxf(sqrtf(ss), 1e-7f)) * w0 * cwb[row];
    ushort4 p;
    p.x = f2bf(x[0] * scale); p.y = f2bf(x[1] * scale);
    p.z = f2bf(x[2] * scale); p.w = f2bf(x[3] * scale);
    *(ushort4*)(vlds + (size_t)row * PAD_ + c * 4) = p;
  }
  // ---- Phase 1b: normalize U rows (wave wv owns rows [wv*32, +32)) ----
#pragma unroll 4
  for (int i = 0; i < 8; ++i) {
    int row = wv * 32 + i * 4 + g;
    f32x4 x = *(const f32x4*)(ub + (size_t)row * E_ + c * 4);
    float ss = x[0] * x[0] + x[1] * x[1] + x[2] * x[2] + x[3] * x[3];
    ss += __shfl_xor(ss, 1); ss += __shfl_xor(ss, 2);
    ss += __shfl_xor(ss, 4); ss += __shfl_xor(ss, 8);
    float scale = 1.0f / fmaxf(sqrtf(ss), 1e-7f);
    ushort4 p;
    p.x = f2bf(x[0] * scale); p.y = f2bf(x[1] * scale);
    p.z = f2bf(x[2] * scale); p.w = f2bf(x[3] * scale);
    *(ushort4*)(ulds + (size_t)row * PAD_ + c * 4) = p;
  }

  // mask -> per-lane bitmask (lane's column class is c; n = it*16 + c)
  const float* __restrict__ mb = mask + (size_t)b * S_;
  unsigned int mbits = 0;
#pragma unroll
  for (int i = 0; i < 32; ++i)
    mbits |= (mb[i * 16 + c] > 0.5f ? 1u : 0u) << i;

  __syncthreads();

  // ---- Phase 2: wave wv owns 32 s-rows [wv*32, +32); scan all 512 n ----
  const unsigned short* ur = ulds + (size_t)(wv * 32 + c) * PAD_ + g * 8;
  bf16x8 a00 = *(const bf16x8*)(ur);
  bf16x8 a01 = *(const bf16x8*)(ur + 32);
  bf16x8 a10 = *(const bf16x8*)(ur + 16 * PAD_);
  bf16x8 a11 = *(const bf16x8*)(ur + 16 * PAD_ + 32);

  float r0[4] = {-INFINITY, -INFINITY, -INFINITY, -INFINITY};
  float r1[4] = {-INFINITY, -INFINITY, -INFINITY, -INFINITY};

#pragma unroll 4
  for (int it = 0; it < 32; ++it) {
    const unsigned short* vr = vlds + (size_t)(it * 16 + c) * PAD_ + g * 8;
    bf16x8 b0 = *(const bf16x8*)(vr);
    bf16x8 b1 = *(const bf16x8*)(vr + 32);
    f32x4 acc0 = {0.f, 0.f, 0.f, 0.f};
    f32x4 acc1 = {0.f, 0.f, 0.f, 0.f};
    acc0 = __builtin_amdgcn_mfma_f32_16x16x32_bf16(a00, b0, acc0, 0, 0, 0);
    acc0 = __builtin_amdgcn_mfma_f32_16x16x32_bf16(a01, b1, acc0, 0, 0, 0);
    acc1 = __builtin_amdgcn_mfma_f32_16x16x32_bf16(a10, b0, acc1, 0, 0, 0);
    acc1 = __builtin_amdgcn_mfma_f32_16x16x32_bf16(a11, b1, acc1, 0, 0, 0);
    bool keep = (mbits >> it) & 1u;
#pragma unroll
    for (int i = 0; i < 4; ++i) {
      r0[i] = fmaxf(r0[i], keep ? acc0[i] : -INFINITY);
      r1[i] = fmaxf(r1[i], keep ? acc1[i] : -INFINITY);
    }
  }

  // max over the 16 column-lanes (xor 1,2,4,8 stays within kg group)
#pragma unroll
  for (int i = 0; i < 4; ++i) {
    float v = r0[i];
    v = fmaxf(v, __shfl_xor(v, 1)); v = fmaxf(v, __shfl_xor(v, 2));
    v = fmaxf(v, __shfl_xor(v, 4)); v = fmaxf(v, __shfl_xor(v, 8));
    r0[i] = v;
    v = r1[i];
    v = fmaxf(v, __shfl_xor(v, 1)); v = fmaxf(v, __shfl_xor(v, 2));
    v = fmaxf(v, __shfl_xor(v, 4)); v = fmaxf(v, __shfl_xor(v, 8));
    r1[i] = v;
  }

  if (c == 0) {
    float bias = pb[0];
    size_t base = (size_t)b * S_ + shalf * 256 + wv * 32;
#pragma unroll
    for (int i = 0; i < 4; ++i) {
      float v = r0[i];
      out[base + g * 4 + i] =
          (v < -1e30f) ? 0.0f : 1.0f / (1.0f + expf(-(v + bias)));
      v = r1[i];
      out[base + 16 + g * 4 + i] =
          (v < -1e30f) ? 0.0f : 1.0f / (1.0f + expf(-(v + bias)));
    }
  }
}

extern "C" void kernel_launch(void* const* d_in, const int* in_sizes, int n_in,
                              void* d_out, int out_size, void* d_ws, size_t ws_size,
                              hipStream_t stream) {
  const float* ue = (const float*)d_in[0];
  const float* ve = (const float*)d_in[1];
  const float* cw = (const float*)d_in[2];
  const float* mask = (const float*)d_in[3];
  const float* pw = (const float*)d_in[4];
  const float* pb = (const float*)d_in[5];
  float* out = (float*)d_out;

  hipLaunchKernelGGL(fused_kernel, dim3(2 * B_), dim3(512), 0, stream,
                     ue, ve, cw, mask, pw, pb, out);
}

// Round 3
// 18.796 us; speedup vs baseline: 3.0906x; 1.1237x over previous
//
#include <hip/hip_runtime.h>
#include <math.h>

#define B_ 128
#define S_ 512
#define E_ 64
#define PAD_ 72  // bf16 elems per LDS row (144 B): bank-uniform ds_read_b128

typedef short bf16x8 __attribute__((ext_vector_type(8)));
typedef float f32x4 __attribute__((ext_vector_type(4)));

__device__ __forceinline__ unsigned short f2bf(float f) {
  union { float f; unsigned int u; } v; v.f = f;
  unsigned int u = v.u;
  return (unsigned short)((u + 0x7fffu + ((u >> 16) & 1u)) >> 16);
}

// One block (1024 thr, 16 waves) per (batch b, s-half). Phase 1: register-staged
// normalize of V (512 rows, fold w*cw) and U (256 rows) into LDS bf16.
// Phase 2: wave (ws,wn) owns 64 s-rows x 128 n; mask via MFMA C-init penalty.
__global__ __launch_bounds__(1024) void fused_kernel(
    const float* __restrict__ ue, const float* __restrict__ ve,
    const float* __restrict__ cw, const float* __restrict__ mask,
    const float* __restrict__ pw, const float* __restrict__ pb,
    float* __restrict__ out) {
  __shared__ unsigned short vlds[S_ * PAD_];   // 73728 B
  __shared__ unsigned short ulds[256 * PAD_];  // 36864 B
  __shared__ float comb[4][256];               // 4096 B

  // XCD pair-swizzle: both s-halves of a batch land on the same XCD (8 XCDs,
  // default round-robin blockIdx->XCD), so the 2nd V read is an L2 hit.
  const int bx = blockIdx.x;
  const int b = (bx & 7) * 16 + ((bx >> 3) >> 1);
  const int shalf = (bx >> 3) & 1;

  const int tid = threadIdx.x;
  const int wv = tid >> 6;
  const int lane = tid & 63;
  const int c = lane & 15;  // column class / element group
  const int g = lane >> 4;  // row-within-4 / k-group
  const int ws = wv >> 2;   // s-split (0..3): 64 s-rows
  const int wn = wv & 3;    // n-split (0..3): 128 n

  const float w0 = pw[0];
  const float* __restrict__ vb = ve + (size_t)b * S_ * E_;
  const float* __restrict__ cwb = cw + (size_t)b * S_;
  const float* __restrict__ ub = ue + ((size_t)b * S_ + shalf * 256) * E_;
  const float* __restrict__ mb = mask + (size_t)b * S_;

  // ---- Stage ALL phase-1 loads first (maximize loads in flight) ----
  f32x4 vs[8];
  float cws[8];
#pragma unroll
  for (int i = 0; i < 8; ++i) {
    int row = wv * 32 + i * 4 + g;
    vs[i] = *(const f32x4*)(vb + (size_t)row * E_ + c * 4);
    cws[i] = cwb[row];
  }
  f32x4 us[4];
#pragma unroll
  for (int i = 0; i < 4; ++i) {
    int row = wv * 16 + i * 4 + g;
    us[i] = *(const f32x4*)(ub + (size_t)row * E_ + c * 4);
  }
  float pen[8];  // per-lane column penalty for this wave's 8 n-tiles
#pragma unroll
  for (int j = 0; j < 8; ++j)
    pen[j] = (mb[(wn * 8 + j) * 16 + c] > 0.5f) ? 0.0f : -1e30f;

  // ---- Process V: normalize + fold w0*cw, emit bf16 to LDS ----
#pragma unroll
  for (int i = 0; i < 8; ++i) {
    f32x4 x = vs[i];
    float ss = x[0] * x[0] + x[1] * x[1] + x[2] * x[2] + x[3] * x[3];
    ss += __shfl_xor(ss, 1); ss += __shfl_xor(ss, 2);
    ss += __shfl_xor(ss, 4); ss += __shfl_xor(ss, 8);
    float scale = (1.0f / fmaxf(sqrtf(ss), 1e-7f)) * w0 * cws[i];
    ushort4 p;
    p.x = f2bf(x[0] * scale); p.y = f2bf(x[1] * scale);
    p.z = f2bf(x[2] * scale); p.w = f2bf(x[3] * scale);
    int row = wv * 32 + i * 4 + g;
    *(ushort4*)(vlds + (size_t)row * PAD_ + c * 4) = p;
  }
  // ---- Process U: normalize, emit bf16 to LDS ----
#pragma unroll
  for (int i = 0; i < 4; ++i) {
    f32x4 x = us[i];
    float ss = x[0] * x[0] + x[1] * x[1] + x[2] * x[2] + x[3] * x[3];
    ss += __shfl_xor(ss, 1); ss += __shfl_xor(ss, 2);
    ss += __shfl_xor(ss, 4); ss += __shfl_xor(ss, 8);
    float scale = 1.0f / fmaxf(sqrtf(ss), 1e-7f);
    ushort4 p;
    p.x = f2bf(x[0] * scale); p.y = f2bf(x[1] * scale);
    p.z = f2bf(x[2] * scale); p.w = f2bf(x[3] * scale);
    int row = wv * 16 + i * 4 + g;
    *(ushort4*)(ulds + (size_t)row * PAD_ + c * 4) = p;
  }

  __syncthreads();

  // ---- Phase 2: A-fragments for 4 s-tiles (rows ws*64 + st*16 + c) ----
  const unsigned short* urp = ulds + (size_t)(ws * 64 + c) * PAD_ + g * 8;
  bf16x8 a[4][2];
#pragma unroll
  for (int st = 0; st < 4; ++st) {
    a[st][0] = *(const bf16x8*)(urp + st * 16 * PAD_);
    a[st][1] = *(const bf16x8*)(urp + st * 16 * PAD_ + 32);
  }

  float r[4][4];
#pragma unroll
  for (int st = 0; st < 4; ++st)
#pragma unroll
    for (int i = 0; i < 4; ++i) r[st][i] = -INFINITY;

#pragma unroll
  for (int j = 0; j < 8; ++j) {
    int it = wn * 8 + j;
    const unsigned short* vr = vlds + (size_t)(it * 16 + c) * PAD_ + g * 8;
    bf16x8 b0 = *(const bf16x8*)(vr);
    bf16x8 b1 = *(const bf16x8*)(vr + 32);
    f32x4 ci = {pen[j], pen[j], pen[j], pen[j]};
#pragma unroll
    for (int st = 0; st < 4; ++st) {
      f32x4 acc = __builtin_amdgcn_mfma_f32_16x16x32_bf16(a[st][0], b0, ci, 0, 0, 0);
      acc = __builtin_amdgcn_mfma_f32_16x16x32_bf16(a[st][1], b1, acc, 0, 0, 0);
      r[st][0] = fmaxf(r[st][0], acc[0]);
      r[st][1] = fmaxf(r[st][1], acc[1]);
      r[st][2] = fmaxf(r[st][2], acc[2]);
      r[st][3] = fmaxf(r[st][3], acc[3]);
    }
  }

  // ---- Reduce over the 16 column-lanes (xor 1,2,4,8 stays in kg group) ----
#pragma unroll
  for (int st = 0; st < 4; ++st)
#pragma unroll
    for (int i = 0; i < 4; ++i) {
      float v = r[st][i];
      v = fmaxf(v, __shfl_xor(v, 1)); v = fmaxf(v, __shfl_xor(v, 2));
      v = fmaxf(v, __shfl_xor(v, 4)); v = fmaxf(v, __shfl_xor(v, 8));
      r[st][i] = v;
    }

  if (c == 0) {
#pragma unroll
    for (int st = 0; st < 4; ++st)
#pragma unroll
      for (int i = 0; i < 4; ++i)
        comb[wn][ws * 64 + st * 16 + g * 4 + i] = r[st][i];
  }

  __syncthreads();

  // ---- Final: n-split combine + sigmoid, 256 outputs ----
  if (tid < 256) {
    float v = fmaxf(fmaxf(comb[0][tid], comb[1][tid]),
                    fmaxf(comb[2][tid], comb[3][tid]));
    float bias = pb[0];
    out[(size_t)b * S_ + shalf * 256 + tid] =
        (v < -1e29f) ? 0.0f : 1.0f / (1.0f + expf(-(v + bias)));
  }
}

extern "C" void kernel_launch(void* const* d_in, const int* in_sizes, int n_in,
                              void* d_out, int out_size, void* d_ws, size_t ws_size,
                              hipStream_t stream) {
  const float* ue = (const float*)d_in[0];
  const float* ve = (const float*)d_in[1];
  const float* cw = (const float*)d_in[2];
  const float* mask = (const float*)d_in[3];
  const float* pw = (const float*)d_in[4];
  const float* pb = (const float*)d_in[5];
  float* out = (float*)d_out;

  hipLaunchKernelGGL(fused_kernel, dim3(2 * B_), dim3(1024), 0, stream,
                     ue, ve, cw, mask, pw, pb, out);
}